// Round 1
// baseline (754.162 us; speedup 1.0000x reference)
//
#include <hip/hip_runtime.h>
#include <hip/hip_fp16.h>

// ---- problem constants ----
#define NU 8192
#define NS 8192
#define D  512
#define C  1000
#define TAU_INV_LOG2E 14.42695040888963f

// output flat offsets (floats)
#define O_OUT1 49545216ull
#define O_OUT2 57737216ull

typedef __attribute__((ext_vector_type(8))) _Float16 half8;
typedef __attribute__((ext_vector_type(4))) float floatx4;

#define MFMA16(a, b, c) __builtin_amdgcn_mfma_f32_16x16x32_f16(a, b, c, 0, 0, 0)

// ---------------- fused pass-through copy + label extract + histogram ----------------
// float4 grid-stride over all 5 pass-through regions (49,545,216 floats).
// While copying the one-hot region, recover labels[] and per-branch class histogram.
__global__ __launch_bounds__(256) void copy_fused(
    const float4* __restrict__ a, const float4* __restrict__ p,
    const float4* __restrict__ l, const float4* __restrict__ oh,
    const float4* __restrict__ lg, float4* __restrict__ out,
    int* __restrict__ labels, int* __restrict__ hist) {
  size_t stride = (size_t)gridDim.x * 256;
  for (size_t i = (size_t)blockIdx.x * 256 + threadIdx.x; i < 12386304ull; i += stride) {
    float4 v;
    if (i < 1048576)       v = a[i];
    else if (i < 2097152)  v = p[i - 1048576];
    else if (i < 4194304)  v = l[i - 2097152];
    else if (i < 8290304) {
      v = oh[i - 4194304];
      float vv[4] = {v.x, v.y, v.z, v.w};
      #pragma unroll
      for (int j = 0; j < 4; ++j)
        if (vv[j] > 0.5f) {
          int fo = (int)((i - 4194304) * 4) + j;
          int row = fo / 1000, c = fo - row * 1000;
          labels[row] = c;
          atomicAdd(&hist[(row >> 13) * 1024 + c], 1);
        }
    } else                 v = lg[i - 8290304];
    out[i] = v;
  }
}

// ---------------- exclusive prefix scan (per branch) ----------------
__global__ __launch_bounds__(1024) void scan_kernel(const int* __restrict__ hist,
                                                    int* __restrict__ cursor) {
  __shared__ int s[1024];
  int b = blockIdx.x, t = threadIdx.x;
  int h = hist[b * 1024 + t];
  s[t] = h;
  __syncthreads();
  for (int o = 1; o < 1024; o <<= 1) {
    int v = (t >= o) ? s[t - o] : 0;
    __syncthreads();
    s[t] += v;
    __syncthreads();
  }
  cursor[b * 1024 + t] = s[t] - h;  // exclusive
}

// ---------------- row L2-normalize + f32->f16 (+ sorted scatter for lb) ----------------
// one wave per row, 8 rows per 512-thread block
__global__ __launch_bounds__(512) void normalize_rows(
    const float* __restrict__ anchor, const float* __restrict__ positive,
    const float* __restrict__ lbf, const int* __restrict__ labels,
    int* __restrict__ cursor, int* __restrict__ slab,
    __half* __restrict__ q1, __half* __restrict__ q2, __half* __restrict__ kh) {
  int w = threadIdx.x >> 6, lane = threadIdx.x & 63;
  int row = blockIdx.x * 8 + w;
  const float* base;
  __half* dst;
  if (row < 8192)       { base = anchor + (size_t)row * D;            dst = q1 + (size_t)row * D; }
  else if (row < 16384) { base = positive + (size_t)(row - 8192) * D; dst = q2 + (size_t)(row - 8192) * D; }
  else {
    int lrow = row - 16384, br = lrow >> 13;
    base = lbf + (size_t)lrow * D;
    int pos = 0;
    if (lane == 0) {
      int c = labels[lrow];
      pos = atomicAdd(&cursor[br * 1024 + c], 1);
      slab[br * 8192 + pos] = c;
    }
    pos = __shfl(pos, 0);
    dst = kh + ((size_t)br * 8192 + pos) * D;
  }
  float4 x = *(const float4*)(base + lane * 8);
  float4 y = *(const float4*)(base + lane * 8 + 4);
  float ss = x.x * x.x + x.y * x.y + x.z * x.z + x.w * x.w +
             y.x * y.x + y.y * y.y + y.z * y.z + y.w * y.w;
  #pragma unroll
  for (int o = 1; o < 64; o <<= 1) ss += __shfl_xor(ss, o);
  float rs = rsqrtf(ss);
  half8 h;
  h[0] = (_Float16)(x.x * rs); h[1] = (_Float16)(x.y * rs);
  h[2] = (_Float16)(x.z * rs); h[3] = (_Float16)(x.w * rs);
  h[4] = (_Float16)(y.x * rs); h[5] = (_Float16)(y.y * rs);
  h[6] = (_Float16)(y.z * rs); h[7] = (_Float16)(y.w * rs);
  *(half8*)(dst + lane * 8) = h;
}

// ---- async K staging: 128 rows x 256 halves (D-half), XOR-swizzled 16B chunks ----
// LDS_phys[row][ch] = K[s0+row][h*256 + (ch ^ (row&7))*8 ..+8]; rows 512 B contiguous.
__device__ __forceinline__ void stage_half_tile(const __half* __restrict__ kbase,
                                                int s0, int h, char* buf, int w, int lane) {
  int ch = lane & 31, rsel = lane >> 5;
  #pragma unroll
  for (int n = 0; n < 8; ++n) {
    int row = w * 16 + n * 2 + rsel;
    const __half* g = kbase + (size_t)(s0 + row) * D + h * 256 + ((ch ^ (row & 7)) << 3);
    char* ld = buf + (w * 16 + n * 2) * 512;
    __builtin_amdgcn_global_load_lds((const __attribute__((address_space(1))) void*)g,
                                     (__attribute__((address_space(3))) void*)ld, 16, 0, 0);
  }
}

// ---- E/St swizzled addressing: 64 rows x 256 B, XOR on 16B-chunk index ----
// byte = row*256 + (colb ^ (s(row)<<4)),  s(row) = (row&7) ^ ((row>>3)&1).
// Reads (row varies with l15 per quarter-wave) become 2-way (free); the
// (row>>3) parity bit keeps the exp-phase b16 writes (rows l4*4 apart)
// from aliasing onto the same bank words.
__device__ __forceinline__ int est_off(int row, int colb) {
  int s = (row & 7) ^ ((row >> 3) & 1);
  return row * 256 + (colb ^ (s << 4));
}

// ---------------- main fused kernel ----------------
// grid (128, 2), 512 threads (8 waves, 2x4 over 64 q-rows x 128 supports).
// Q-resident in VGPRs; K double-buffered via global_load_lds; E/St overlay K0 buffer;
// sorted labels -> 64-slot ring window; final in-place softmax normalization.
__global__ __launch_bounds__(512, 2) void paws_main(
    const __half* __restrict__ q1, const __half* __restrict__ q2,
    const __half* __restrict__ kh, const int* __restrict__ slab,
    float* __restrict__ out) {
  __shared__ __align__(16) char bufA[65536];
  __shared__ __align__(16) char bufB[65536];
  __shared__ float win[64][65];
  __shared__ float denp[8][32];
  __shared__ float den_final[64];

  int b = blockIdx.y;
  const __half* q  = b ? q2 : q1;
  const __half* kb = kh + (size_t)b * NS * D;
  const int* lab   = slab + b * NS;
  float* num = out + (b ? O_OUT2 : O_OUT1);

  int tid = threadIdx.x, w = tid >> 6, lane = tid & 63;
  int l15 = lane & 15, l4 = lane >> 4;
  int wr = w >> 2, wc = w & 3;   // 2x4 wave grid
  int qrow0 = blockIdx.x * 64;
  int swz = l15 & 7;

  // ---- Q-resident A fragments: 2 row-tiles x 16 k-chunks = 128 VGPRs ----
  half8 af[2][16];
  #pragma unroll
  for (int i = 0; i < 2; ++i)
    #pragma unroll
    for (int kc = 0; kc < 16; ++kc)
      af[i][kc] = *(const half8*)(q + (size_t)(qrow0 + wr * 32 + i * 16 + l15) * D + kc * 32 + l4 * 8);

  for (int i = tid; i < 64 * 65; i += 512) ((float*)win)[i] = 0.f;

  // prime: K0(t=0) -> bufA
  stage_half_tile(kb, 0, 0, bufA, w, lane);
  __syncthreads();  // win init visible + K0 drained

  float dacc[2][4];
  #pragma unroll
  for (int i = 0; i < 2; ++i)
    #pragma unroll
    for (int r = 0; r < 4; ++r) dacc[i][r] = 0.f;
  int flush_from = 0;

  for (int t = 0; t < 64; ++t) {
    int s0 = t * 128;
    char* X = (t & 1) ? bufB : bufA;  // holds K0(t) (prefetched)
    char* Y = (t & 1) ? bufA : bufB;  // free (held E/St(t-1))
    char* Ep  = X;                    // 64 rows x 256 B, swizzled
    char* Stp = X + 16384;            // 64 slots x 256 B, swizzled

    // issue K1(t) -> Y (overlaps flush + kc0..7)
    stage_half_tile(kb, s0, 1, Y, w, lane);

    // flush completed classes [flush_from, c_lo)
    int c_lo = lab[s0];
    if (c_lo > flush_from) {
      for (int r = w; r < 64; r += 8) {
        float* rowp = num + (size_t)(qrow0 + r) * C;
        for (int c = flush_from + lane; c < c_lo; c += 64) {
          int slot = c & 63;
          rowp[c] = win[r][slot];
          win[r][slot] = 0.f;
        }
      }
      flush_from = c_lo;
    }

    // ---- QK^T: kc 0..7 on X (K0) ----
    floatx4 acc[2][2];
    #pragma unroll
    for (int i = 0; i < 2; ++i)
      #pragma unroll
      for (int j = 0; j < 2; ++j) acc[i][j] = (floatx4)0.f;

    #pragma unroll
    for (int kcl = 0; kcl < 8; ++kcl) {
      int chx = (((kcl * 4 + l4) ^ swz) << 4);
      const char* r0 = X + (size_t)(wc * 32 + l15) * 512 + chx;
      half8 bf0 = *(const half8*)r0;
      half8 bf1 = *(const half8*)(r0 + 16 * 512);
      acc[0][0] = MFMA16(af[0][kcl], bf0, acc[0][0]);
      acc[1][0] = MFMA16(af[1][kcl], bf0, acc[1][0]);
      acc[0][1] = MFMA16(af[0][kcl], bf1, acc[0][1]);
      acc[1][1] = MFMA16(af[1][kcl], bf1, acc[1][1]);
    }
    __syncthreads();  // #1: drains K1(t); X k-reads done

    // St zero (cols 0..127) — X's K0 consumed; overlaps kc8..15
    {
      int zrow = tid >> 3;
      int cb0 = (tid & 7) << 5;
      *(uint4*)(Stp + est_off(zrow, cb0))      = (uint4){0, 0, 0, 0};
      *(uint4*)(Stp + est_off(zrow, cb0 + 16)) = (uint4){0, 0, 0, 0};
    }

    // ---- QK^T: kc 8..15 on Y (K1) ----
    #pragma unroll
    for (int kcl = 0; kcl < 8; ++kcl) {
      int chx = (((kcl * 4 + l4) ^ swz) << 4);
      const char* r0 = Y + (size_t)(wc * 32 + l15) * 512 + chx;
      half8 bf0 = *(const half8*)r0;
      half8 bf1 = *(const half8*)(r0 + 16 * 512);
      acc[0][0] = MFMA16(af[0][8 + kcl], bf0, acc[0][0]);
      acc[1][0] = MFMA16(af[1][8 + kcl], bf0, acc[1][0]);
      acc[0][1] = MFMA16(af[0][8 + kcl], bf1, acc[0][1]);
      acc[1][1] = MFMA16(af[1][8 + kcl], bf1, acc[1][1]);
    }
    __syncthreads();  // #2: St zeros complete; Y k-reads done

    // ---- exp -> E (f16, C-layout transposed into A-layout via LDS), St set ----
    #pragma unroll
    for (int i = 0; i < 2; ++i)
      #pragma unroll
      for (int j = 0; j < 2; ++j)
        #pragma unroll
        for (int r = 0; r < 4; ++r) {
          float e = exp2f(acc[i][j][r] * TAU_INV_LOG2E);
          dacc[i][r] += e;
          int erow = wr * 32 + i * 16 + l4 * 4 + r;
          *(__half*)(Ep + est_off(erow, (wc * 32 + j * 16 + l15) * 2)) = __float2half(e);
        }
    if (tid < 128) {
      int slot = lab[s0 + tid] & 63;
      *(__half*)(Stp + est_off(slot, tid * 2)) = __float2half(1.f);
    }
    __syncthreads();  // #3: E/St ready

    // prefetch K0(t+1) -> Y (overlaps W-phase; Y's reads drained at #2)
    if (t < 63) stage_half_tile(kb, s0 + 128, 0, Y, w, lane);

    // ---- W = E(64x128) @ St(128x64): per-class tile sums -> ring window ----
    floatx4 wacc0 = (floatx4)0.f, wacc1 = (floatx4)0.f;
    #pragma unroll
    for (int kk = 0; kk < 4; ++kk) {
      int colb = kk * 64 + l4 * 16;
      half8 ea0 = *(const half8*)(Ep + est_off(wr * 32 + l15, colb));
      half8 ea1 = *(const half8*)(Ep + est_off(wr * 32 + 16 + l15, colb));
      half8 sb  = *(const half8*)(Stp + est_off(wc * 16 + l15, colb));
      wacc0 = MFMA16(ea0, sb, wacc0);
      wacc1 = MFMA16(ea1, sb, wacc1);
    }
    #pragma unroll
    for (int r = 0; r < 4; ++r) {
      win[wr * 32 + l4 * 4 + r][wc * 16 + l15] += wacc0[r];
      win[wr * 32 + 16 + l4 * 4 + r][wc * 16 + l15] += wacc1[r];
    }
    __syncthreads();  // #4: win updates done; X free; K0(t+1) drained
  }

  // ---- final flush [flush_from, C) ----
  for (int r = w; r < 64; r += 8) {
    float* rowp = num + (size_t)(qrow0 + r) * C;
    for (int c = flush_from + lane; c < C; c += 64) {
      rowp[c] = win[r][c & 63];
    }
  }

  // ---- denominators -> LDS ----
  #pragma unroll
  for (int i = 0; i < 2; ++i)
    #pragma unroll
    for (int r = 0; r < 4; ++r) {
      float v = dacc[i][r];
      v += __shfl_xor(v, 1);
      v += __shfl_xor(v, 2);
      v += __shfl_xor(v, 4);
      v += __shfl_xor(v, 8);
      if (l15 == 0) denp[w][i * 16 + l4 * 4 + r] = v;
    }
  __syncthreads();
  if (tid < 64) {
    int wr2 = tid >> 5, rl = tid & 31;
    den_final[tid] = denp[wr2 * 4 + 0][rl] + denp[wr2 * 4 + 1][rl] +
                     denp[wr2 * 4 + 2][rl] + denp[wr2 * 4 + 3][rl];
  }
  __syncthreads();

  // ---- in-place softmax normalization of owned rows ----
  for (int r = w; r < 64; r += 8) {
    float inv = 1.0f / den_final[r];
    float* rowp = num + (size_t)(qrow0 + r) * C;
    for (int c = lane; c < C; c += 64) rowp[c] *= inv;
  }
}

extern "C" void kernel_launch(void* const* d_in, const int* in_sizes, int n_in,
                              void* d_out, int out_size, void* d_ws, size_t ws_size,
                              hipStream_t stream) {
  const float* anchor    = (const float*)d_in[0];
  const float* positive  = (const float*)d_in[1];
  const float* lbf       = (const float*)d_in[2];
  const float* oh        = (const float*)d_in[3];
  const float* logits_lb = (const float*)d_in[4];
  float* out = (float*)d_out;

  char* ws = (char*)d_ws;
  __half* q1  = (__half*)ws;                   //  8 MB
  __half* q2  = (__half*)(ws + 8388608);       //  8 MB
  __half* kh  = (__half*)(ws + 16777216);      // 16 MB (sorted-by-label, per branch)
  int* labels = (int*)(ws + 33554432);         // 64 KB
  int* slab   = (int*)(ws + 33619968);         // 64 KB (sorted labels)
  int* hist   = (int*)(ws + 33685504);         //  8 KB
  int* cursor = (int*)(ws + 33693696);         //  8 KB

  hipMemsetAsync(hist, 0, 8192, stream);

  copy_fused<<<4096, 256, 0, stream>>>(
      (const float4*)anchor, (const float4*)positive, (const float4*)lbf,
      (const float4*)oh, (const float4*)logits_lb, (float4*)out, labels, hist);
  scan_kernel<<<2, 1024, 0, stream>>>(hist, cursor);
  normalize_rows<<<4096, 512, 0, stream>>>(anchor, positive, lbf, labels, cursor,
                                           slab, q1, q2, kh);
  paws_main<<<dim3(128, 2), 512, 0, stream>>>(q1, q2, kh, slab, out);
}

// Round 3
// 747.072 us; speedup vs baseline: 1.0095x; 1.0095x over previous
//
#include <hip/hip_runtime.h>
#include <hip/hip_fp16.h>

// ---- problem constants ----
#define NU 8192
#define NS 8192
#define D  512
#define C  1000
#define TAU_INV_LOG2E 14.42695040888963f

// output flat offsets (floats)
#define O_OUT1 49545216ull
#define O_OUT2 57737216ull

typedef __attribute__((ext_vector_type(8))) _Float16 half8;
typedef __attribute__((ext_vector_type(4))) float floatx4;

#define MFMA16(a, b, c) __builtin_amdgcn_mfma_f32_16x16x32_f16(a, b, c, 0, 0, 0)

// ---------------- generic float4 streaming copy ----------------
__global__ __launch_bounds__(256) void copy4(const float4* __restrict__ src,
                                             float4* __restrict__ dst,
                                             unsigned n4) {
  unsigned stride = gridDim.x * 256;
  for (unsigned i = blockIdx.x * 256 + threadIdx.x; i < n4; i += stride)
    dst[i] = src[i];
}

// ---------------- one-hot copy + label extract + histogram ----------------
__global__ __launch_bounds__(256) void oh_copy(
    const float4* __restrict__ oh, float4* __restrict__ outoh,
    int* __restrict__ labels, int* __restrict__ hist) {
  unsigned stride = gridDim.x * 256;
  for (unsigned i = blockIdx.x * 256 + threadIdx.x; i < 4096000u; i += stride) {
    float4 v = oh[i];
    float vv[4] = {v.x, v.y, v.z, v.w};
    #pragma unroll
    for (int j = 0; j < 4; ++j)
      if (vv[j] > 0.5f) {
        int fo = (int)(i * 4) + j;
        int row = fo / 1000, c = fo - row * 1000;
        labels[row] = c;
        atomicAdd(&hist[(row >> 13) * 1024 + c], 1);
      }
    outoh[i] = v;
  }
}

// ---------------- exclusive prefix scan (per branch) ----------------
__global__ __launch_bounds__(1024) void scan_kernel(const int* __restrict__ hist,
                                                    int* __restrict__ cursor) {
  __shared__ int s[1024];
  int b = blockIdx.x, t = threadIdx.x;
  int h = hist[b * 1024 + t];
  s[t] = h;
  __syncthreads();
  for (int o = 1; o < 1024; o <<= 1) {
    int v = (t >= o) ? s[t - o] : 0;
    __syncthreads();
    s[t] += v;
    __syncthreads();
  }
  cursor[b * 1024 + t] = s[t] - h;  // exclusive
}

// ---------------- row L2-normalize + f32->f16 (+ sorted scatter for lb) ----------------
// one wave per row, 8 rows per 512-thread block
__global__ __launch_bounds__(512) void normalize_rows(
    const float* __restrict__ anchor, const float* __restrict__ positive,
    const float* __restrict__ lbf, const int* __restrict__ labels,
    int* __restrict__ cursor, int* __restrict__ slab,
    __half* __restrict__ q1, __half* __restrict__ q2, __half* __restrict__ kh) {
  int w = threadIdx.x >> 6, lane = threadIdx.x & 63;
  int row = blockIdx.x * 8 + w;
  const float* base;
  __half* dst;
  if (row < 8192)       { base = anchor + (size_t)row * D;            dst = q1 + (size_t)row * D; }
  else if (row < 16384) { base = positive + (size_t)(row - 8192) * D; dst = q2 + (size_t)(row - 8192) * D; }
  else {
    int lrow = row - 16384, br = lrow >> 13;
    base = lbf + (size_t)lrow * D;
    int pos = 0;
    if (lane == 0) {
      int c = labels[lrow];
      pos = atomicAdd(&cursor[br * 1024 + c], 1);
      slab[br * 8192 + pos] = c;
    }
    pos = __shfl(pos, 0);
    dst = kh + ((size_t)br * 8192 + pos) * D;
  }
  float4 x = *(const float4*)(base + lane * 8);
  float4 y = *(const float4*)(base + lane * 8 + 4);
  float ss = x.x * x.x + x.y * x.y + x.z * x.z + x.w * x.w +
             y.x * y.x + y.y * y.y + y.z * y.z + y.w * y.w;
  #pragma unroll
  for (int o = 1; o < 64; o <<= 1) ss += __shfl_xor(ss, o);
  float rs = rsqrtf(ss);
  half8 h;
  h[0] = (_Float16)(x.x * rs); h[1] = (_Float16)(x.y * rs);
  h[2] = (_Float16)(x.z * rs); h[3] = (_Float16)(x.w * rs);
  h[4] = (_Float16)(y.x * rs); h[5] = (_Float16)(y.y * rs);
  h[6] = (_Float16)(y.z * rs); h[7] = (_Float16)(y.w * rs);
  *(half8*)(dst + lane * 8) = h;
}

// ---- async K staging: 128 rows x 256 halves (D-half), XOR-swizzled 16B chunks ----
// LDS_phys[row][ch] = K[s0+row][h*256 + (ch ^ (row&7))*8 ..+8]; rows 512 B contiguous.
__device__ __forceinline__ void stage_half_tile(const __half* __restrict__ kbase,
                                                int s0, int h, char* buf, int w, int lane) {
  int ch = lane & 31, rsel = lane >> 5;
  #pragma unroll
  for (int n = 0; n < 8; ++n) {
    int row = w * 16 + n * 2 + rsel;
    const __half* g = kbase + (size_t)(s0 + row) * D + h * 256 + ((ch ^ (row & 7)) << 3);
    char* ld = buf + (w * 16 + n * 2) * 512;
    __builtin_amdgcn_global_load_lds((const __attribute__((address_space(1))) void*)g,
                                     (__attribute__((address_space(3))) void*)ld, 16, 0, 0);
  }
}

// ---------------- main fused kernel ----------------
// grid (128, 2), 512 threads (8 waves, 2x4 over 64 q-rows x 128 supports).
// Q-resident in VGPRs; K double-buffered via global_load_lds; E/St overlay K0 buffer;
// sorted labels -> 64-slot ring window; final in-place softmax normalization.
__global__ __launch_bounds__(512, 2) void paws_main(
    const __half* __restrict__ q1, const __half* __restrict__ q2,
    const __half* __restrict__ kh, const int* __restrict__ slab,
    float* __restrict__ out) {
  __shared__ __align__(16) char bufA[65536];
  __shared__ __align__(16) char bufB[65536];
  __shared__ float win[64][65];
  __shared__ float denp[8][32];
  __shared__ float den_final[64];

  int b = blockIdx.y;
  const __half* q  = b ? q2 : q1;
  const __half* kb = kh + (size_t)b * NS * D;
  const int* lab   = slab + b * NS;
  float* num = out + (b ? O_OUT2 : O_OUT1);

  int tid = threadIdx.x, w = tid >> 6, lane = tid & 63;
  int l15 = lane & 15, l4 = lane >> 4;
  int wr = w >> 2, wc = w & 3;   // 2x4 wave grid
  int qrow0 = blockIdx.x * 64;
  int swz = l15 & 7;

  // ---- Q-resident A fragments: 2 row-tiles x 16 k-chunks = 128 VGPRs ----
  half8 af[2][16];
  #pragma unroll
  for (int i = 0; i < 2; ++i)
    #pragma unroll
    for (int kc = 0; kc < 16; ++kc)
      af[i][kc] = *(const half8*)(q + (size_t)(qrow0 + wr * 32 + i * 16 + l15) * D + kc * 32 + l4 * 8);

  for (int i = tid; i < 64 * 65; i += 512) ((float*)win)[i] = 0.f;

  // prime: K0(t=0) -> bufA
  stage_half_tile(kb, 0, 0, bufA, w, lane);
  __syncthreads();  // win init visible + K0 drained

  float dacc[2][4];
  #pragma unroll
  for (int i = 0; i < 2; ++i)
    #pragma unroll
    for (int r = 0; r < 4; ++r) dacc[i][r] = 0.f;
  int flush_from = 0;

  for (int t = 0; t < 64; ++t) {
    int s0 = t * 128;
    char* X = (t & 1) ? bufB : bufA;  // holds K0(t) (prefetched)
    char* Y = (t & 1) ? bufA : bufB;  // free (held E/St(t-1))
    __half* Ep  = (__half*)X;
    __half* Stp = (__half*)(X + 18432);

    // issue K1(t) -> Y (overlaps flush + kc0..7)
    stage_half_tile(kb, s0, 1, Y, w, lane);

    // flush completed classes [flush_from, c_lo)
    int c_lo = lab[s0];
    if (c_lo > flush_from) {
      for (int r = w; r < 64; r += 8) {
        float* rowp = num + (size_t)(qrow0 + r) * C;
        for (int c = flush_from + lane; c < c_lo; c += 64) {
          int slot = c & 63;
          rowp[c] = win[r][slot];
          win[r][slot] = 0.f;
        }
      }
      flush_from = c_lo;
    }

    // ---- QK^T: kc 0..7 on X (K0) ----
    floatx4 acc[2][2];
    #pragma unroll
    for (int i = 0; i < 2; ++i)
      #pragma unroll
      for (int j = 0; j < 2; ++j) acc[i][j] = (floatx4)0.f;

    #pragma unroll
    for (int kcl = 0; kcl < 8; ++kcl) {
      int chx = (((kcl * 4 + l4) ^ swz) << 4);
      const char* r0 = X + (size_t)(wc * 32 + l15) * 512 + chx;
      half8 bf0 = *(const half8*)r0;
      half8 bf1 = *(const half8*)(r0 + 16 * 512);
      acc[0][0] = MFMA16(af[0][kcl], bf0, acc[0][0]);
      acc[1][0] = MFMA16(af[1][kcl], bf0, acc[1][0]);
      acc[0][1] = MFMA16(af[0][kcl], bf1, acc[0][1]);
      acc[1][1] = MFMA16(af[1][kcl], bf1, acc[1][1]);
    }
    __syncthreads();  // #1: drains K1(t); X k-reads done

    // St zero (cols 0..127) — X's K0 consumed; overlaps kc8..15
    {
      __half* z = Stp + (tid >> 3) * 144 + (tid & 7) * 16;
      *(uint4*)z = (uint4){0, 0, 0, 0};
      *(uint4*)(z + 8) = (uint4){0, 0, 0, 0};
    }

    // ---- QK^T: kc 8..15 on Y (K1) ----
    #pragma unroll
    for (int kcl = 0; kcl < 8; ++kcl) {
      int chx = (((kcl * 4 + l4) ^ swz) << 4);
      const char* r0 = Y + (size_t)(wc * 32 + l15) * 512 + chx;
      half8 bf0 = *(const half8*)r0;
      half8 bf1 = *(const half8*)(r0 + 16 * 512);
      acc[0][0] = MFMA16(af[0][8 + kcl], bf0, acc[0][0]);
      acc[1][0] = MFMA16(af[1][8 + kcl], bf0, acc[1][0]);
      acc[0][1] = MFMA16(af[0][8 + kcl], bf1, acc[0][1]);
      acc[1][1] = MFMA16(af[1][8 + kcl], bf1, acc[1][1]);
    }
    __syncthreads();  // #2: St zeros complete; Y k-reads done

    // ---- exp -> E (f16, C-layout transposed into A-layout via LDS), St set ----
    #pragma unroll
    for (int i = 0; i < 2; ++i)
      #pragma unroll
      for (int j = 0; j < 2; ++j)
        #pragma unroll
        for (int r = 0; r < 4; ++r) {
          float e = exp2f(acc[i][j][r] * TAU_INV_LOG2E);
          dacc[i][r] += e;
          Ep[(size_t)(wr * 32 + i * 16 + l4 * 4 + r) * 144 + (wc * 32 + j * 16 + l15)] = __float2half(e);
        }
    if (tid < 128) Stp[(size_t)(lab[s0 + tid] & 63) * 144 + tid] = __float2half(1.f);
    __syncthreads();  // #3: E/St ready

    // prefetch K0(t+1) -> Y (overlaps W-phase; Y's reads drained at #2)
    if (t < 63) stage_half_tile(kb, s0 + 128, 0, Y, w, lane);

    // ---- W = E(64x128) @ St(128x64): per-class tile sums -> ring window ----
    floatx4 wacc0 = (floatx4)0.f, wacc1 = (floatx4)0.f;
    #pragma unroll
    for (int kk = 0; kk < 4; ++kk) {
      half8 ea0 = *(const half8*)(Ep + (size_t)(wr * 32 + l15) * 144 + kk * 32 + l4 * 8);
      half8 ea1 = *(const half8*)(Ep + (size_t)(wr * 32 + 16 + l15) * 144 + kk * 32 + l4 * 8);
      half8 sb  = *(const half8*)(Stp + (size_t)(wc * 16 + l15) * 144 + kk * 32 + l4 * 8);
      wacc0 = MFMA16(ea0, sb, wacc0);
      wacc1 = MFMA16(ea1, sb, wacc1);
    }
    #pragma unroll
    for (int r = 0; r < 4; ++r) {
      win[wr * 32 + l4 * 4 + r][wc * 16 + l15] += wacc0[r];
      win[wr * 32 + 16 + l4 * 4 + r][wc * 16 + l15] += wacc1[r];
    }
    __syncthreads();  // #4: win updates done; X free; K0(t+1) drained
  }

  // ---- final flush [flush_from, C) ----
  for (int r = w; r < 64; r += 8) {
    float* rowp = num + (size_t)(qrow0 + r) * C;
    for (int c = flush_from + lane; c < C; c += 64) {
      rowp[c] = win[r][c & 63];
    }
  }

  // ---- denominators -> LDS ----
  #pragma unroll
  for (int i = 0; i < 2; ++i)
    #pragma unroll
    for (int r = 0; r < 4; ++r) {
      float v = dacc[i][r];
      v += __shfl_xor(v, 1);
      v += __shfl_xor(v, 2);
      v += __shfl_xor(v, 4);
      v += __shfl_xor(v, 8);
      if (l15 == 0) denp[w][i * 16 + l4 * 4 + r] = v;
    }
  __syncthreads();
  if (tid < 64) {
    int wr2 = tid >> 5, rl = tid & 31;
    den_final[tid] = denp[wr2 * 4 + 0][rl] + denp[wr2 * 4 + 1][rl] +
                     denp[wr2 * 4 + 2][rl] + denp[wr2 * 4 + 3][rl];
  }
  __syncthreads();

  // ---- in-place softmax normalization of owned rows ----
  for (int r = w; r < 64; r += 8) {
    float inv = 1.0f / den_final[r];
    float* rowp = num + (size_t)(qrow0 + r) * C;
    for (int c = lane; c < C; c += 64) rowp[c] *= inv;
  }
}

extern "C" void kernel_launch(void* const* d_in, const int* in_sizes, int n_in,
                              void* d_out, int out_size, void* d_ws, size_t ws_size,
                              hipStream_t stream) {
  const float* anchor    = (const float*)d_in[0];
  const float* positive  = (const float*)d_in[1];
  const float* lbf       = (const float*)d_in[2];
  const float* oh        = (const float*)d_in[3];
  const float* logits_lb = (const float*)d_in[4];
  float* out = (float*)d_out;

  char* ws = (char*)d_ws;
  __half* q1  = (__half*)ws;                   //  8 MB
  __half* q2  = (__half*)(ws + 8388608);       //  8 MB
  __half* kh  = (__half*)(ws + 16777216);      // 16 MB (sorted-by-label, per branch)
  int* labels = (int*)(ws + 33554432);         // 64 KB
  int* slab   = (int*)(ws + 33619968);         // 64 KB (sorted labels)
  int* hist   = (int*)(ws + 33685504);         //  8 KB
  int* cursor = (int*)(ws + 33693696);         //  8 KB

  hipMemsetAsync(hist, 0, 8192, stream);

  // oh region (labels needed) through the kernel; float4 index base 4194304
  oh_copy<<<2048, 256, 0, stream>>>(
      (const float4*)oh, (float4*)out + 4194304, labels, hist);
  scan_kernel<<<2, 1024, 0, stream>>>(hist, cursor);
  normalize_rows<<<4096, 512, 0, stream>>>(anchor, positive, lbf, labels, cursor,
                                           slab, q1, q2, kh);
  paws_main<<<dim3(128, 2), 512, 0, stream>>>(q1, q2, kh, slab, out);

  // pure pass-through regions via streaming copy kernels
  copy4<<<2048, 256, 0, stream>>>((const float4*)anchor,
                                  (float4*)out, 1048576u);
  copy4<<<2048, 256, 0, stream>>>((const float4*)positive,
                                  (float4*)out + 1048576, 1048576u);
  copy4<<<2048, 256, 0, stream>>>((const float4*)lbf,
                                  (float4*)out + 2097152, 2097152u);
  copy4<<<2048, 256, 0, stream>>>((const float4*)logits_lb,
                                  (float4*)out + 8290304, 4096000u);
}

// Round 4
// 735.807 us; speedup vs baseline: 1.0249x; 1.0153x over previous
//
#include <hip/hip_runtime.h>
#include <hip/hip_fp16.h>

// ---- problem constants ----
#define NU 8192
#define NS 8192
#define D  512
#define C  1000
#define TAU_INV_LOG2E 14.42695040888963f

// output flat offsets (floats)
#define O_OUT1 49545216ull
#define O_OUT2 57737216ull

typedef __attribute__((ext_vector_type(8))) _Float16 half8;
typedef __attribute__((ext_vector_type(4))) float floatx4;

#define MFMA16(a, b, c) __builtin_amdgcn_mfma_f32_16x16x32_f16(a, b, c, 0, 0, 0)

// ---------------- fused aux kernel ----------------
// blocks [0,3072): grid-stride float4 copy of oh (+label/hist extract),
//                  logits, lbf regions.
// blocks [3072,5120): row-per-wave anchor/positive: single read feeds both
//                  the f32 pass-through copy and normalized f16 q1/q2.
__global__ __launch_bounds__(512) void aux_fused(
    const float4* __restrict__ a4, const float4* __restrict__ p4,
    const float4* __restrict__ l4, const float4* __restrict__ oh4,
    const float4* __restrict__ lg4, float4* __restrict__ out4,
    const float* __restrict__ a, const float* __restrict__ p,
    __half* __restrict__ q1, __half* __restrict__ q2,
    int* __restrict__ labels, int* __restrict__ hist) {
  if (blockIdx.x < 3072) {
    unsigned stride = 3072u * 512u;
    for (unsigned i = blockIdx.x * 512 + threadIdx.x; i < 10289152u; i += stride) {
      float4 v;
      unsigned dst;
      if (i < 4096000u) {                     // one-hot region
        v = oh4[i];
        float vv[4] = {v.x, v.y, v.z, v.w};
        #pragma unroll
        for (int j = 0; j < 4; ++j)
          if (vv[j] > 0.5f) {
            int fo = (int)(i * 4) + j;
            int row = fo / 1000, c = fo - row * 1000;
            labels[row] = c;
            atomicAdd(&hist[(row >> 13) * 1024 + c], 1);
          }
        dst = 4194304u + i;
      } else if (i < 8192000u) {              // logits region
        v = lg4[i - 4096000u];
        dst = 8290304u + (i - 4096000u);
      } else {                                // lbf region (copy only)
        v = l4[i - 8192000u];
        dst = 2097152u + (i - 8192000u);
      }
      out4[dst] = v;
    }
  } else {
    int w = threadIdx.x >> 6, lane = threadIdx.x & 63;
    int row = (blockIdx.x - 3072) * 8 + w;    // 0..16383
    const float* base;
    __half* dst;
    unsigned o4;
    if (row < 8192) {
      base = a + (size_t)row * D;
      dst  = q1 + (size_t)row * D;
      o4   = (unsigned)row * 128u;
    } else {
      base = p + (size_t)(row - 8192) * D;
      dst  = q2 + (size_t)(row - 8192) * D;
      o4   = 1048576u + (unsigned)(row - 8192) * 128u;
    }
    float4 x = *(const float4*)(base + lane * 8);
    float4 y = *(const float4*)(base + lane * 8 + 4);
    out4[o4 + lane * 2]     = x;              // f32 pass-through copy
    out4[o4 + lane * 2 + 1] = y;
    float ss = x.x * x.x + x.y * x.y + x.z * x.z + x.w * x.w +
               y.x * y.x + y.y * y.y + y.z * y.z + y.w * y.w;
    #pragma unroll
    for (int o = 1; o < 64; o <<= 1) ss += __shfl_xor(ss, o);
    float rs = rsqrtf(ss);
    half8 h;
    h[0] = (_Float16)(x.x * rs); h[1] = (_Float16)(x.y * rs);
    h[2] = (_Float16)(x.z * rs); h[3] = (_Float16)(x.w * rs);
    h[4] = (_Float16)(y.x * rs); h[5] = (_Float16)(y.y * rs);
    h[6] = (_Float16)(y.z * rs); h[7] = (_Float16)(y.w * rs);
    *(half8*)(dst + lane * 8) = h;
  }
}

// ---------------- exclusive prefix scan (per branch) ----------------
__global__ __launch_bounds__(1024) void scan_kernel(const int* __restrict__ hist,
                                                    int* __restrict__ cursor) {
  __shared__ int s[1024];
  int b = blockIdx.x, t = threadIdx.x;
  int h = hist[b * 1024 + t];
  s[t] = h;
  __syncthreads();
  for (int o = 1; o < 1024; o <<= 1) {
    int v = (t >= o) ? s[t - o] : 0;
    __syncthreads();
    s[t] += v;
    __syncthreads();
  }
  cursor[b * 1024 + t] = s[t] - h;  // exclusive
}

// ---------------- lb rows: normalize + f16 + sorted scatter ----------------
// one wave per row (re-reads lbf, likely L3-warm from aux_fused's copy)
__global__ __launch_bounds__(512) void lb_normscatter(
    const float* __restrict__ lbf, const int* __restrict__ labels,
    int* __restrict__ cursor, int* __restrict__ slab, __half* __restrict__ kh) {
  int w = threadIdx.x >> 6, lane = threadIdx.x & 63;
  int row = blockIdx.x * 8 + w;               // 0..16383
  int br = row >> 13;
  const float* base = lbf + (size_t)row * D;
  int pos = 0;
  if (lane == 0) {
    int c = labels[row];
    pos = atomicAdd(&cursor[br * 1024 + c], 1);
    slab[br * 8192 + pos] = c;
  }
  pos = __shfl(pos, 0);
  __half* dst = kh + ((size_t)br * 8192 + pos) * D;
  float4 x = *(const float4*)(base + lane * 8);
  float4 y = *(const float4*)(base + lane * 8 + 4);
  float ss = x.x * x.x + x.y * x.y + x.z * x.z + x.w * x.w +
             y.x * y.x + y.y * y.y + y.z * y.z + y.w * y.w;
  #pragma unroll
  for (int o = 1; o < 64; o <<= 1) ss += __shfl_xor(ss, o);
  float rs = rsqrtf(ss);
  half8 h;
  h[0] = (_Float16)(x.x * rs); h[1] = (_Float16)(x.y * rs);
  h[2] = (_Float16)(x.z * rs); h[3] = (_Float16)(x.w * rs);
  h[4] = (_Float16)(y.x * rs); h[5] = (_Float16)(y.y * rs);
  h[6] = (_Float16)(y.z * rs); h[7] = (_Float16)(y.w * rs);
  *(half8*)(dst + lane * 8) = h;
}

// ---- async K staging: 128 rows x 256 halves (D-half), XOR-swizzled 16B chunks ----
// LDS_phys[row][ch] = K[s0+row][h*256 + (ch ^ (row&7))*8 ..+8]; rows 512 B contiguous.
__device__ __forceinline__ void stage_half_tile(const __half* __restrict__ kbase,
                                                int s0, int h, char* buf, int w, int lane) {
  int ch = lane & 31, rsel = lane >> 5;
  #pragma unroll
  for (int n = 0; n < 8; ++n) {
    int row = w * 16 + n * 2 + rsel;
    const __half* g = kbase + (size_t)(s0 + row) * D + h * 256 + ((ch ^ (row & 7)) << 3);
    char* ld = buf + (w * 16 + n * 2) * 512;
    __builtin_amdgcn_global_load_lds((const __attribute__((address_space(1))) void*)g,
                                     (__attribute__((address_space(3))) void*)ld, 16, 0, 0);
  }
}

// ---------------- main fused kernel ----------------
// grid (128, 2), 512 threads (8 waves, 2x4 over 64 q-rows x 128 supports).
// Q-resident in VGPRs; K double-buffered via global_load_lds; E/St overlay K0 buffer;
// sorted labels -> 64-slot ring window; final in-place softmax normalization.
__global__ __launch_bounds__(512, 2) void paws_main(
    const __half* __restrict__ q1, const __half* __restrict__ q2,
    const __half* __restrict__ kh, const int* __restrict__ slab,
    float* __restrict__ out) {
  __shared__ __align__(16) char bufA[65536];
  __shared__ __align__(16) char bufB[65536];
  __shared__ float win[64][65];
  __shared__ float denp[8][32];
  __shared__ float den_final[64];

  int b = blockIdx.y;
  const __half* q  = b ? q2 : q1;
  const __half* kb = kh + (size_t)b * NS * D;
  const int* lab   = slab + b * NS;
  float* num = out + (b ? O_OUT2 : O_OUT1);

  int tid = threadIdx.x, w = tid >> 6, lane = tid & 63;
  int l15 = lane & 15, l4 = lane >> 4;
  int wr = w >> 2, wc = w & 3;   // 2x4 wave grid
  int qrow0 = blockIdx.x * 64;
  int swz = l15 & 7;

  // ---- Q-resident A fragments: 2 row-tiles x 16 k-chunks = 128 VGPRs ----
  half8 af[2][16];
  #pragma unroll
  for (int i = 0; i < 2; ++i)
    #pragma unroll
    for (int kc = 0; kc < 16; ++kc)
      af[i][kc] = *(const half8*)(q + (size_t)(qrow0 + wr * 32 + i * 16 + l15) * D + kc * 32 + l4 * 8);

  for (int i = tid; i < 64 * 65; i += 512) ((float*)win)[i] = 0.f;

  // prime: K0(t=0) -> bufA
  stage_half_tile(kb, 0, 0, bufA, w, lane);
  __syncthreads();  // win init visible + K0 drained

  float dacc[2][4];
  #pragma unroll
  for (int i = 0; i < 2; ++i)
    #pragma unroll
    for (int r = 0; r < 4; ++r) dacc[i][r] = 0.f;
  int flush_from = 0;

  for (int t = 0; t < 64; ++t) {
    int s0 = t * 128;
    char* X = (t & 1) ? bufB : bufA;  // holds K0(t) (prefetched)
    char* Y = (t & 1) ? bufA : bufB;  // free (held E/St(t-1))
    __half* Ep  = (__half*)X;
    __half* Stp = (__half*)(X + 18432);

    // issue K1(t) -> Y (overlaps flush + kc0..7)
    stage_half_tile(kb, s0, 1, Y, w, lane);

    // flush completed classes [flush_from, c_lo)
    int c_lo = lab[s0];
    if (c_lo > flush_from) {
      for (int r = w; r < 64; r += 8) {
        float* rowp = num + (size_t)(qrow0 + r) * C;
        for (int c = flush_from + lane; c < c_lo; c += 64) {
          int slot = c & 63;
          rowp[c] = win[r][slot];
          win[r][slot] = 0.f;
        }
      }
      flush_from = c_lo;
    }

    // ---- QK^T: kc 0..7 on X (K0) ----
    floatx4 acc[2][2];
    #pragma unroll
    for (int i = 0; i < 2; ++i)
      #pragma unroll
      for (int j = 0; j < 2; ++j) acc[i][j] = (floatx4)0.f;

    #pragma unroll
    for (int kcl = 0; kcl < 8; ++kcl) {
      int chx = (((kcl * 4 + l4) ^ swz) << 4);
      const char* r0 = X + (size_t)(wc * 32 + l15) * 512 + chx;
      half8 bf0 = *(const half8*)r0;
      half8 bf1 = *(const half8*)(r0 + 16 * 512);
      acc[0][0] = MFMA16(af[0][kcl], bf0, acc[0][0]);
      acc[1][0] = MFMA16(af[1][kcl], bf0, acc[1][0]);
      acc[0][1] = MFMA16(af[0][kcl], bf1, acc[0][1]);
      acc[1][1] = MFMA16(af[1][kcl], bf1, acc[1][1]);
    }
    __syncthreads();  // #1: drains K1(t); X k-reads done

    // St zero (cols 0..127) — X's K0 consumed; overlaps kc8..15
    {
      __half* z = Stp + (tid >> 3) * 144 + (tid & 7) * 16;
      *(uint4*)z = (uint4){0, 0, 0, 0};
      *(uint4*)(z + 8) = (uint4){0, 0, 0, 0};
    }

    // ---- QK^T: kc 8..15 on Y (K1) ----
    #pragma unroll
    for (int kcl = 0; kcl < 8; ++kcl) {
      int chx = (((kcl * 4 + l4) ^ swz) << 4);
      const char* r0 = Y + (size_t)(wc * 32 + l15) * 512 + chx;
      half8 bf0 = *(const half8*)r0;
      half8 bf1 = *(const half8*)(r0 + 16 * 512);
      acc[0][0] = MFMA16(af[0][8 + kcl], bf0, acc[0][0]);
      acc[1][0] = MFMA16(af[1][8 + kcl], bf0, acc[1][0]);
      acc[0][1] = MFMA16(af[0][8 + kcl], bf1, acc[0][1]);
      acc[1][1] = MFMA16(af[1][8 + kcl], bf1, acc[1][1]);
    }
    __syncthreads();  // #2: St zeros complete; Y k-reads done

    // ---- exp -> E (f16, C-layout transposed into A-layout via LDS), St set ----
    #pragma unroll
    for (int i = 0; i < 2; ++i)
      #pragma unroll
      for (int j = 0; j < 2; ++j)
        #pragma unroll
        for (int r = 0; r < 4; ++r) {
          float e = exp2f(acc[i][j][r] * TAU_INV_LOG2E);
          dacc[i][r] += e;
          Ep[(size_t)(wr * 32 + i * 16 + l4 * 4 + r) * 144 + (wc * 32 + j * 16 + l15)] = __float2half(e);
        }
    if (tid < 128) Stp[(size_t)(lab[s0 + tid] & 63) * 144 + tid] = __float2half(1.f);
    __syncthreads();  // #3: E/St ready

    // prefetch K0(t+1) -> Y (overlaps W-phase; Y's reads drained at #2)
    if (t < 63) stage_half_tile(kb, s0 + 128, 0, Y, w, lane);

    // ---- W = E(64x128) @ St(128x64): per-class tile sums -> ring window ----
    floatx4 wacc0 = (floatx4)0.f, wacc1 = (floatx4)0.f;
    #pragma unroll
    for (int kk = 0; kk < 4; ++kk) {
      half8 ea0 = *(const half8*)(Ep + (size_t)(wr * 32 + l15) * 144 + kk * 32 + l4 * 8);
      half8 ea1 = *(const half8*)(Ep + (size_t)(wr * 32 + 16 + l15) * 144 + kk * 32 + l4 * 8);
      half8 sb  = *(const half8*)(Stp + (size_t)(wc * 16 + l15) * 144 + kk * 32 + l4 * 8);
      wacc0 = MFMA16(ea0, sb, wacc0);
      wacc1 = MFMA16(ea1, sb, wacc1);
    }
    #pragma unroll
    for (int r = 0; r < 4; ++r) {
      win[wr * 32 + l4 * 4 + r][wc * 16 + l15] += wacc0[r];
      win[wr * 32 + 16 + l4 * 4 + r][wc * 16 + l15] += wacc1[r];
    }
    __syncthreads();  // #4: win updates done; X free; K0(t+1) drained
  }

  // ---- final flush [flush_from, C) ----
  for (int r = w; r < 64; r += 8) {
    float* rowp = num + (size_t)(qrow0 + r) * C;
    for (int c = flush_from + lane; c < C; c += 64) {
      rowp[c] = win[r][c & 63];
    }
  }

  // ---- denominators -> LDS ----
  #pragma unroll
  for (int i = 0; i < 2; ++i)
    #pragma unroll
    for (int r = 0; r < 4; ++r) {
      float v = dacc[i][r];
      v += __shfl_xor(v, 1);
      v += __shfl_xor(v, 2);
      v += __shfl_xor(v, 4);
      v += __shfl_xor(v, 8);
      if (l15 == 0) denp[w][i * 16 + l4 * 4 + r] = v;
    }
  __syncthreads();
  if (tid < 64) {
    int wr2 = tid >> 5, rl = tid & 31;
    den_final[tid] = denp[wr2 * 4 + 0][rl] + denp[wr2 * 4 + 1][rl] +
                     denp[wr2 * 4 + 2][rl] + denp[wr2 * 4 + 3][rl];
  }
  __syncthreads();

  // ---- in-place softmax normalization of owned rows ----
  for (int r = w; r < 64; r += 8) {
    float inv = 1.0f / den_final[r];
    float* rowp = num + (size_t)(qrow0 + r) * C;
    for (int c = lane; c < C; c += 64) rowp[c] *= inv;
  }
}

extern "C" void kernel_launch(void* const* d_in, const int* in_sizes, int n_in,
                              void* d_out, int out_size, void* d_ws, size_t ws_size,
                              hipStream_t stream) {
  const float* anchor    = (const float*)d_in[0];
  const float* positive  = (const float*)d_in[1];
  const float* lbf       = (const float*)d_in[2];
  const float* oh        = (const float*)d_in[3];
  const float* logits_lb = (const float*)d_in[4];
  float* out = (float*)d_out;

  char* ws = (char*)d_ws;
  __half* q1  = (__half*)ws;                   //  8 MB
  __half* q2  = (__half*)(ws + 8388608);       //  8 MB
  __half* kh  = (__half*)(ws + 16777216);      // 16 MB (sorted-by-label, per branch)
  int* labels = (int*)(ws + 33554432);         // 64 KB
  int* slab   = (int*)(ws + 33619968);         // 64 KB (sorted labels)
  int* hist   = (int*)(ws + 33685504);         //  8 KB
  int* cursor = (int*)(ws + 33693696);         //  8 KB

  hipMemsetAsync(hist, 0, 8192, stream);

  aux_fused<<<5120, 512, 0, stream>>>(
      (const float4*)anchor, (const float4*)positive, (const float4*)lbf,
      (const float4*)oh, (const float4*)logits_lb, (float4*)out,
      anchor, positive, q1, q2, labels, hist);
  scan_kernel<<<2, 1024, 0, stream>>>(hist, cursor);
  lb_normscatter<<<2048, 512, 0, stream>>>(lbf, labels, cursor, slab, kh);
  paws_main<<<dim3(128, 2), 512, 0, stream>>>(q1, q2, kh, slab, out);
}